// Round 1
// baseline (352.554 us; speedup 1.0000x reference)
//
#include <hip/hip_runtime.h>
#include <stdint.h>

typedef short v8s __attribute__((ext_vector_type(8)));
typedef float v4f __attribute__((ext_vector_type(4)));
typedef unsigned int u32;

#define LOG2E 1.44269504088896340736f

__device__ __forceinline__ unsigned short bfr(float x) {
  union { float f; u32 u; } t; t.f = x;
  u32 r = t.u + 0x7FFFu + ((t.u >> 16) & 1u);
  return (unsigned short)(r >> 16);
}

__device__ __forceinline__ void async16(const void* g, void* l) {
  __builtin_amdgcn_global_load_lds(
      (const __attribute__((address_space(1))) u32*)g,
      (__attribute__((address_space(3))) u32*)l, 16, 0, 0);
}

// ---------- cast hidden fp32 -> bf16 ----------
__global__ void cast_h_kernel(const float4* __restrict__ in, ushort4* __restrict__ out, int n4) {
  int i = blockIdx.x * blockDim.x + threadIdx.x;
  if (i < n4) {
    float4 v = in[i];
    ushort4 o;
    o.x = bfr(v.x); o.y = bfr(v.y); o.z = bfr(v.z); o.w = bfr(v.w);
    out[i] = o;
  }
}

// ---------- transpose-cast W [1024 x 1024] f32 -> Wt [N x K] bf16 (scaled) ----------
__global__ void transpose_cast_kernel(const float* __restrict__ in, unsigned short* __restrict__ out,
                                      float scale) {
  __shared__ float tile[32][33];
  const int N = 1024, K = 1024;
  int n0 = blockIdx.x * 32, k0 = blockIdx.y * 32;
  int tx = threadIdx.x, ty = threadIdx.y;
#pragma unroll
  for (int j = 0; j < 32; j += 8)
    tile[ty + j][tx] = in[(size_t)(k0 + ty + j) * N + n0 + tx];
  __syncthreads();
#pragma unroll
  for (int j = 0; j < 32; j += 8)
    out[(size_t)(n0 + ty + j) * K + k0 + tx] = bfr(tile[tx][ty + j] * scale);
}

// ---------- transpose V [bh][2048][64] -> Vt [bh][64][2048] ----------
__global__ void transpose_v_kernel(const unsigned short* __restrict__ V, unsigned short* __restrict__ Vt) {
  __shared__ unsigned short t[64][65];
  int bh = blockIdx.y;
  int s0 = blockIdx.x * 64;
  const unsigned short* src = V + (size_t)bh * 2048 * 64;
  unsigned short* dst = Vt + (size_t)bh * 64 * 2048;
  int tx = threadIdx.x, ty = threadIdx.y;
#pragma unroll
  for (int j = 0; j < 64; j += 4)
    t[ty + j][tx] = src[(size_t)(s0 + ty + j) * 64 + tx];
  __syncthreads();
#pragma unroll
  for (int j = 0; j < 64; j += 4)
    dst[(size_t)(ty + j) * 2048 + s0 + tx] = t[tx][ty + j];
}

// ---------- GEMM: C[M x N] = A[M x 1024] @ Bt[N x 1024]^T  (bf16 in, fp32 acc) ----------
// EPI 0: write C as bf16 scattered into Q/K/V [B,H,S,D] (contiguous buffers, sel = col>>10)
// EPI 1: write C as fp32 to outF with bias
template <int EPI>
__global__ __launch_bounds__(256)
void gemm_bt_kernel(const unsigned short* __restrict__ A,
                    const unsigned short* __restrict__ Bt,
                    unsigned short* __restrict__ qkv,
                    float* __restrict__ outF,
                    const float* __restrict__ bias) {
  __shared__ __align__(16) unsigned short As[128 * 32];
  __shared__ __align__(16) unsigned short Bs[128 * 32];
  const int tid = threadIdx.x;
  const int wid = tid >> 6;
  const int lane = tid & 63;
  const int quad = lane >> 4;
  const int l16 = lane & 15;
  const int tile_m = blockIdx.y * 128;
  const int tile_n = blockIdx.x * 128;

  // staging: wave w covers rows [w*32, w*32+32), 2 issues of 16 rows (64B rows)
  const int srow = wid * 32 + (lane >> 2);
  const int scol = (lane & 3) * 8;
  const unsigned short* ag = A + (size_t)(tile_m + srow) * 1024 + scol;
  const unsigned short* bg = Bt + (size_t)(tile_n + srow) * 1024 + scol;
  unsigned short* al = &As[srow * 32 + scol];
  unsigned short* bl = &Bs[srow * 32 + scol];

  v4f zero = {0.f, 0.f, 0.f, 0.f};
  v4f acc[4][4];
#pragma unroll
  for (int i = 0; i < 4; ++i)
#pragma unroll
    for (int j = 0; j < 4; ++j) acc[i][j] = zero;

  const int wm = (wid >> 1) * 64;
  const int wn = (wid & 1) * 64;

  for (int k0 = 0; k0 < 1024; k0 += 32) {
    async16(ag + k0, al);
    async16(ag + k0 + 16 * 1024, al + 16 * 32);
    async16(bg + k0, bl);
    async16(bg + k0 + 16 * 1024, bl + 16 * 32);
    __syncthreads();
    v8s a[4], b[4];
#pragma unroll
    for (int i = 0; i < 4; ++i)
      a[i] = *(const v8s*)&As[(wm + i * 16 + l16) * 32 + quad * 8];
#pragma unroll
    for (int j = 0; j < 4; ++j)
      b[j] = *(const v8s*)&Bs[(wn + j * 16 + l16) * 32 + quad * 8];
#pragma unroll
    for (int i = 0; i < 4; ++i)
#pragma unroll
      for (int j = 0; j < 4; ++j)
        acc[i][j] = __builtin_amdgcn_mfma_f32_16x16x32_bf16(a[i], b[j], acc[i][j], 0, 0, 0);
    __syncthreads();
  }

#pragma unroll
  for (int i = 0; i < 4; ++i)
#pragma unroll
    for (int j = 0; j < 4; ++j)
#pragma unroll
      for (int r = 0; r < 4; ++r) {
        int row = tile_m + wm + i * 16 + quad * 4 + r;
        int col = tile_n + wn + j * 16 + l16;
        float v = acc[i][j][r];
        if (EPI == 0) {
          int sel = col >> 10;
          int h = (col >> 6) & 15;
          int d = col & 63;
          int b_ = row >> 11;
          int s_ = row & 2047;
          qkv[(size_t)sel * 8388608 + (((size_t)(b_ * 16 + h) * 2048 + s_) * 64 + d)] = bfr(v);
        } else {
          outF[(size_t)row * 1024 + col] = v + bias[col];
        }
      }
}

// ---------- flash attention: per (q-tile 128, bh), O = softmax(Q K^T) V ----------
// Q pre-scaled by 0.125 (folded into Wq). LDS = 16+16+16+16 = 64 KB -> 2 blocks/CU.
// All tiles use 16B-chunk XOR swizzle (applied on the GLOBAL address during
// global_load_lds staging so LDS lane-contiguity holds) to break the
// row-stride % 128B == 0 bank patterns.
__global__ __launch_bounds__(256, 2)
void flash_kernel(const unsigned short* __restrict__ Q, const unsigned short* __restrict__ K,
                  const unsigned short* __restrict__ Vt, unsigned short* __restrict__ O) {
  __shared__ __align__(16) unsigned short Qs[128 * 64];
  __shared__ __align__(16) unsigned short Ks[128 * 64];
  __shared__ __align__(16) unsigned short Vts[64 * 128];
  __shared__ __align__(16) unsigned short Ps[128 * 64];  // wave-private rows, reused per kv-half

  const int tid = threadIdx.x;
  const int wid = tid >> 6;
  const int lane = tid & 63;
  const int quad = lane >> 4;
  const int l16 = lane & 15;
  const int bh = blockIdx.y;
  const int q0 = blockIdx.x * 128;
  const unsigned short* Qp = Q + (size_t)bh * (2048 * 64);
  const unsigned short* Kp = K + (size_t)bh * (2048 * 64);
  const unsigned short* Vp = Vt + (size_t)bh * (64 * 2048);

  // stage Q once: rows 0..127 of 64 elems; chunk c in LDS holds global chunk c^(row&7)
  {
    int r0 = wid * 32 + (lane >> 3);
    int c = lane & 7;
#pragma unroll
    for (int it = 0; it < 4; ++it) {
      int rr = r0 + it * 8;
      int cg = c ^ (rr & 7);
      async16(Qp + (size_t)(q0 + rr) * 64 + cg * 8, &Qs[rr * 64 + c * 8]);
    }
  }

  v4f zero = {0.f, 0.f, 0.f, 0.f};
  v4f oacc[2][4];
#pragma unroll
  for (int mi = 0; mi < 2; ++mi)
#pragma unroll
    for (int j = 0; j < 4; ++j) oacc[mi][j] = zero;
  float m_st[2][4], l_st[2][4];
#pragma unroll
  for (int mi = 0; mi < 2; ++mi)
#pragma unroll
    for (int r = 0; r < 4; ++r) { m_st[mi][r] = -1e30f; l_st[mi][r] = 0.f; }

  const int wq = wid * 32;  // wave's local q-row base

  for (int kv0 = 0; kv0 < 2048; kv0 += 128) {
    // stage K tile (same pattern as Q)
    {
      int r0 = wid * 32 + (lane >> 3);
      int c = lane & 7;
#pragma unroll
      for (int it = 0; it < 4; ++it) {
        int rr = r0 + it * 8;
        int cg = c ^ (rr & 7);
        async16(Kp + (size_t)(kv0 + rr) * 64 + cg * 8, &Ks[rr * 64 + c * 8]);
      }
    }
    // stage Vt tile: 64 rows (d) x 128 (kv); 16 chunks/row, swizzle c^(d&15)
    {
      int d0 = wid * 16 + (lane >> 4);
      int c = lane & 15;
#pragma unroll
      for (int it = 0; it < 4; ++it) {
        int dd = d0 + it * 4;
        int cg = c ^ (dd & 15);
        async16(Vp + (size_t)dd * 2048 + kv0 + cg * 8, &Vts[dd * 128 + c * 8]);
      }
    }
    __syncthreads();

    // S = Q K^T  (wave: 32 q x 128 kv)
    v4f s[2][8];
#pragma unroll
    for (int mi = 0; mi < 2; ++mi)
#pragma unroll
      for (int j = 0; j < 8; ++j) s[mi][j] = zero;
#pragma unroll
    for (int ks = 0; ks < 2; ++ks) {
      v8s aq[2], bk[8];
#pragma unroll
      for (int mi = 0; mi < 2; ++mi) {
        int q = wq + mi * 16 + l16;
        int cc = (ks * 4 + quad) ^ (q & 7);
        aq[mi] = *(const v8s*)&Qs[q * 64 + cc * 8];
      }
#pragma unroll
      for (int j = 0; j < 8; ++j) {
        int kvr = j * 16 + l16;
        int cc = (ks * 4 + quad) ^ (kvr & 7);
        bk[j] = *(const v8s*)&Ks[kvr * 64 + cc * 8];
      }
#pragma unroll
      for (int mi = 0; mi < 2; ++mi)
#pragma unroll
        for (int j = 0; j < 8; ++j)
          s[mi][j] = __builtin_amdgcn_mfma_f32_16x16x32_bf16(aq[mi], bk[j], s[mi][j], 0, 0, 0);
    }

    // online softmax: row max, rescale state + O accumulator
#pragma unroll
    for (int mi = 0; mi < 2; ++mi)
#pragma unroll
      for (int r = 0; r < 4; ++r) {
        float mx = s[mi][0][r];
#pragma unroll
        for (int j = 1; j < 8; ++j) mx = fmaxf(mx, s[mi][j][r]);
        mx = fmaxf(mx, __shfl_xor(mx, 1));
        mx = fmaxf(mx, __shfl_xor(mx, 2));
        mx = fmaxf(mx, __shfl_xor(mx, 4));
        mx = fmaxf(mx, __shfl_xor(mx, 8));
        float mnew = fmaxf(m_st[mi][r], mx);
        float a = __builtin_amdgcn_exp2f((m_st[mi][r] - mnew) * LOG2E);
        m_st[mi][r] = mnew;
        l_st[mi][r] *= a;
#pragma unroll
        for (int j = 0; j < 4; ++j) oacc[mi][j][r] *= a;
      }

    // P (C-layout) -> LDS (A-layout rows) in two kv-halves of 64, then PV
#pragma unroll
    for (int half = 0; half < 2; ++half) {
#pragma unroll
      for (int mi = 0; mi < 2; ++mi)
#pragma unroll
        for (int r = 0; r < 4; ++r) {
          int q = wq + mi * 16 + quad * 4 + r;
          float rs = 0.f;
#pragma unroll
          for (int jj = 0; jj < 4; ++jj) {
            int j = half * 4 + jj;
            float p = __builtin_amdgcn_exp2f((s[mi][j][r] - m_st[mi][r]) * LOG2E);
            rs += p;
            int kvl = jj * 16 + l16;
            int cc = (kvl >> 3) ^ (q & 7);
            Ps[q * 64 + cc * 8 + (kvl & 7)] = bfr(p);
          }
          l_st[mi][r] += rs;  // lane-partial row sum (reduced once at the end)
        }
#pragma unroll
      for (int k2 = 0; k2 < 2; ++k2) {
        v8s ap[2], bv[4];
#pragma unroll
        for (int mi = 0; mi < 2; ++mi) {
          int q = wq + mi * 16 + l16;
          int cc = (k2 * 4 + quad) ^ (q & 7);
          ap[mi] = *(const v8s*)&Ps[q * 64 + cc * 8];
        }
#pragma unroll
        for (int j = 0; j < 4; ++j) {
          int d = j * 16 + l16;
          int cc = (half * 8 + k2 * 4 + quad) ^ (d & 15);
          bv[j] = *(const v8s*)&Vts[d * 128 + cc * 8];
        }
#pragma unroll
        for (int mi = 0; mi < 2; ++mi)
#pragma unroll
          for (int j = 0; j < 4; ++j)
            oacc[mi][j] = __builtin_amdgcn_mfma_f32_16x16x32_bf16(ap[mi], bv[j], oacc[mi][j], 0, 0, 0);
      }
    }
    __syncthreads();
  }

  // finalize: reduce l across the 16 cols, normalize, write O as [B,S,H*D] bf16
  float invl[2][4];
#pragma unroll
  for (int mi = 0; mi < 2; ++mi)
#pragma unroll
    for (int r = 0; r < 4; ++r) {
      float l = l_st[mi][r];
      l += __shfl_xor(l, 1);
      l += __shfl_xor(l, 2);
      l += __shfl_xor(l, 4);
      l += __shfl_xor(l, 8);
      invl[mi][r] = 1.0f / l;
    }
  const int b_ = bh >> 4, h_ = bh & 15;
#pragma unroll
  for (int mi = 0; mi < 2; ++mi)
#pragma unroll
    for (int j = 0; j < 4; ++j)
#pragma unroll
      for (int r = 0; r < 4; ++r) {
        int srow = q0 + wq + mi * 16 + quad * 4 + r;
        int col = h_ * 64 + j * 16 + l16;
        O[((size_t)(b_ * 2048 + srow)) * 1024 + col] = bfr(oacc[mi][j][r] * invl[mi][r]);
      }
}

// ---------- launch ----------
// ws layout (MiB offsets): 0 Hb(16, aliased later by Ob) | 16 Wqt(2) | 18 Wkt(2) | 20 Wvt(2)
//                          | 22 Wot(2) | 24 Qb(16) | 40 Kb(16) | 56 Vb(16) | 72 Vtb(16) = 88 total
extern "C" void kernel_launch(void* const* d_in, const int* in_sizes, int n_in,
                              void* d_out, int out_size, void* d_ws, size_t ws_size,
                              hipStream_t stream) {
  const float* Hs = (const float*)d_in[0];
  const float* Wq = (const float*)d_in[1];
  const float* Wk = (const float*)d_in[2];
  const float* Wv = (const float*)d_in[3];
  const float* Wo = (const float*)d_in[4];
  const float* bo = (const float*)d_in[5];
  float* out = (float*)d_out;
  char* ws = (char*)d_ws;
  const size_t MiB = 1ull << 20;
  unsigned short* Hb  = (unsigned short*)(ws);
  unsigned short* Wqt = (unsigned short*)(ws + 16 * MiB);
  unsigned short* Wkt = (unsigned short*)(ws + 18 * MiB);
  unsigned short* Wvt = (unsigned short*)(ws + 20 * MiB);
  unsigned short* Wot = (unsigned short*)(ws + 22 * MiB);
  unsigned short* Qb  = (unsigned short*)(ws + 24 * MiB);
  unsigned short* Vb  = (unsigned short*)(ws + 56 * MiB);
  unsigned short* Vtb = (unsigned short*)(ws + 72 * MiB);
  unsigned short* Kb  = (unsigned short*)(ws + 40 * MiB);
  unsigned short* Ob  = Hb;  // alias: Hb dead after QKV GEMM

  cast_h_kernel<<<8192, 256, 0, stream>>>((const float4*)Hs, (ushort4*)Hb, 2097152);
  transpose_cast_kernel<<<dim3(32, 32), dim3(32, 8), 0, stream>>>(Wq, Wqt, 0.125f);  // fold SCALE
  transpose_cast_kernel<<<dim3(32, 32), dim3(32, 8), 0, stream>>>(Wk, Wkt, 1.0f);
  transpose_cast_kernel<<<dim3(32, 32), dim3(32, 8), 0, stream>>>(Wv, Wvt, 1.0f);
  transpose_cast_kernel<<<dim3(32, 32), dim3(32, 8), 0, stream>>>(Wo, Wot, 1.0f);
  // fused QKV GEMM: Bt = [Wqt|Wkt|Wvt] contiguous => N = 3072
  gemm_bt_kernel<0><<<dim3(24, 64), 256, 0, stream>>>(Hb, Wqt, Qb, nullptr, nullptr);
  transpose_v_kernel<<<dim3(32, 64), dim3(64, 4), 0, stream>>>(Vb, Vtb);
  flash_kernel<<<dim3(16, 64), 256, 0, stream>>>(Qb, Kb, Vtb, Ob);
  gemm_bt_kernel<1><<<dim3(8, 64), 256, 0, stream>>>(Ob, Wot, nullptr, out, bo);
}